// Round 4
// baseline (261.709 us; speedup 1.0000x reference)
//
#include <hip/hip_runtime.h>
#include <hip/hip_bf16.h>

typedef unsigned short u16;
typedef __attribute__((ext_vector_type(8))) short bf16x8;
typedef __attribute__((ext_vector_type(4))) float f32x4;
typedef __attribute__((ext_vector_type(4))) unsigned short u16x4;
typedef __attribute__((ext_vector_type(8))) unsigned short u16x8;

#define BATCH 4096
#define INF   1024
#define NH    4096   // 64 leaves * 64 hidden
#define OUTF  512
#define NLEAF 64
#define FDEPTH 6
#define ZSPL  8      // GEMM2 split-K ways
#define LZ    8      // logits split-K ways

// Scratch as device globals (fully rewritten every call; no ws_size dependency).
__device__ __align__(16) u16  g_Xb[(size_t)BATCH * INF];     // x hi, bf16 (b,k)
__device__ __align__(16) u16  g_Xl[(size_t)BATCH * INF];     // x lo, bf16 (b,k)
__device__ __align__(16) u16  g_W1t[(size_t)NH * INF];       // W1 transposed: (n,k)
__device__ __align__(16) u16  g_W2t[(size_t)OUTF * NH];      // W2 transposed: (o,k)
__device__ __align__(16) u16  g_NWh[(size_t)64 * INF];       // node weights hi (row63=0)
__device__ __align__(16) u16  g_NWl[(size_t)64 * INF];       // node weights lo
__device__ __align__(16) u16  g_Hb[(size_t)BATCH * NH];      // H' = mix*relu(h), bf16
__device__ __align__(16) float g_mix[(size_t)BATCH * NLEAF];
__device__ __align__(16) float g_lpart[(size_t)LZ * BATCH * 64];      // logit partials
__device__ __align__(16) float g_part[(size_t)ZSPL * BATCH * OUTF];   // GEMM2 partials

__device__ inline u16 f2b(float f) {
  __hip_bfloat16 h = __float2bfloat16(f);
  return *reinterpret_cast<u16*>(&h);
}
__device__ inline float b2f(u16 u) {
  __hip_bfloat16 h = *reinterpret_cast<__hip_bfloat16*>(&u);
  return __bfloat162float(h);
}

// Direct global->LDS DMA, 16 B per lane; LDS dest = wave-uniform base + lane*16.
__device__ inline void async16(const u16* g, u16* l) {
  __builtin_amdgcn_global_load_lds((const __attribute__((address_space(1))) void*)g,
                                   (__attribute__((address_space(3))) void*)l, 16, 0, 0);
}

// ---------------- cast x -> bf16 hi + lo ----------------
__global__ __launch_bounds__(256) void cast_x_kernel(const float* __restrict__ x) {
  int i = (blockIdx.x * 256 + threadIdx.x) * 8;
  float4 v0 = *(const float4*)(x + i);
  float4 v1 = *(const float4*)(x + i + 4);
  float vs[8] = {v0.x, v0.y, v0.z, v0.w, v1.x, v1.y, v1.z, v1.w};
  u16x8 h, l;
#pragma unroll
  for (int j = 0; j < 8; ++j) {
    u16 hb = f2b(vs[j]);
    h[j] = hb;
    l[j] = f2b(vs[j] - b2f(hb));
  }
  *(u16x8*)(g_Xb + i) = h;
  *(u16x8*)(g_Xl + i) = l;
}

// ---------------- cast node weights -> hi/lo, row 63 zeroed ----------------
__global__ __launch_bounds__(256) void cast_nw_kernel(const float* __restrict__ nw) {
  int idx = (blockIdx.x * 256 + threadIdx.x) * 4;
  int n = idx >> 10;
  float4 v = make_float4(0.f, 0.f, 0.f, 0.f);
  if (n < 63) v = *(const float4*)(nw + idx);
  float vs[4] = {v.x, v.y, v.z, v.w};
  u16x4 h, l;
#pragma unroll
  for (int j = 0; j < 4; ++j) {
    u16 hb = f2b(vs[j]);
    h[j] = hb;
    l[j] = f2b(vs[j] - b2f(hb));
  }
  *(u16x4*)(g_NWh + idx) = h;
  *(u16x4*)(g_NWl + idx) = l;
}

// ------------- batched transpose + cast: dst[b][c][r] = src[b][r][c] -------------
__global__ __launch_bounds__(256) void transpose_cast_kernel(const float* __restrict__ src,
                                                             int which, int R, int C) {
  __shared__ float tile[64 * 65];
  u16* dstbase = which ? g_W2t : g_W1t;
  const float* sb = src + (size_t)blockIdx.z * R * C;
  u16* db = dstbase + (size_t)blockIdx.z * R * C;
  int r0 = blockIdx.y * 64, c0 = blockIdx.x * 64;
  int t = threadIdx.x;
  int cc4 = (t & 15) * 4;
#pragma unroll
  for (int it = 0; it < 4; ++it) {
    int rr = (t >> 4) + it * 16;
    float4 v = *(const float4*)(sb + (size_t)(r0 + rr) * C + c0 + cc4);
    tile[rr * 65 + cc4 + 0] = v.x;
    tile[rr * 65 + cc4 + 1] = v.y;
    tile[rr * 65 + cc4 + 2] = v.z;
    tile[rr * 65 + cc4 + 3] = v.w;
  }
  __syncthreads();
  int cc = t >> 2, rch = (t & 3) * 16;
  u16x8 o0, o1;
#pragma unroll
  for (int j = 0; j < 8; ++j) o0[j] = f2b(tile[(rch + j) * 65 + cc]);
#pragma unroll
  for (int j = 0; j < 8; ++j) o1[j] = f2b(tile[(rch + 8 + j) * 65 + cc]);
  u16* p = db + (size_t)(c0 + cc) * R + r0 + rch;
  *(u16x8*)p = o0;
  *(u16x8*)(p + 8) = o1;
}

// ------------- logits via MFMA, 3-pass split precision -------------
// m-role = nodes (64), n-role = batch (128/block). KSPLIT=LZ over K=1024.
// logit = Xhi.Whi + Xhi.Wlo + Xlo.Whi  (missing lo.lo term ~1e-6 relative)
__global__ __launch_bounds__(256) void logits_kernel() {
  __shared__ u16 lsX[128 * 64];
  __shared__ u16 lsW[64 * 64];
  const u16* Xs[3] = {g_Xb, g_Xb, g_Xl};
  const u16* Ws[3] = {g_NWh, g_NWl, g_NWh};
  const int t = threadIdx.x;
  const int wv = t >> 6, ln = t & 63;
  const int wm = wv >> 1, wn = wv & 1;  // wm: batch half(64), wn: node half(32)
  const int quad = ln >> 4, m16 = ln & 15;
  const int am0 = blockIdx.y * 128;
  const int kbeg = blockIdx.z * (INF / LZ);
  const int kend = kbeg + INF / LZ;

  f32x4 acc[2][4] = {};  // [tw: node 16-tile][tb: batch 16-tile]

#pragma unroll 1
  for (int p = 0; p < 3; ++p) {
    const u16* __restrict__ Xp = Xs[p];
    const u16* __restrict__ Wp = Ws[p];
    for (int kc = kbeg; kc < kend; kc += 64) {
#pragma unroll
      for (int i = 0; i < 4; ++i) {
        int id = i * 256 + t;
        int row = id >> 3;
        int c8 = (id & 7) ^ (row & 7);
        async16(Xp + (size_t)(am0 + row) * INF + kc + c8 * 8, lsX + (i * 256 + wv * 64) * 8);
      }
#pragma unroll
      for (int i = 0; i < 2; ++i) {
        int id = i * 256 + t;
        int row = id >> 3;
        int c8 = (id & 7) ^ (row & 7);
        async16(Wp + (size_t)row * INF + kc + c8 * 8, lsW + (i * 256 + wv * 64) * 8);
      }
      __syncthreads();
#pragma unroll
      for (int ks = 0; ks < 2; ++ks) {
        bf16x8 wF[2], xF[4];
#pragma unroll
        for (int tw = 0; tw < 2; ++tw) {
          int row = wn * 32 + tw * 16 + m16;
          wF[tw] = *(const bf16x8*)(lsW + row * 64 + ((ks * 4 + quad) ^ (row & 7)) * 8);
        }
#pragma unroll
        for (int tb = 0; tb < 4; ++tb) {
          int row = wm * 64 + tb * 16 + m16;
          xF[tb] = *(const bf16x8*)(lsX + row * 64 + ((ks * 4 + quad) ^ (row & 7)) * 8);
        }
#pragma unroll
        for (int tw = 0; tw < 2; ++tw)
#pragma unroll
          for (int tb = 0; tb < 4; ++tb)
            acc[tw][tb] = __builtin_amdgcn_mfma_f32_16x16x32_bf16(wF[tw], xF[tb], acc[tw][tb], 0, 0, 0);
      }
      __syncthreads();
    }
  }
  float* lp = g_lpart + (size_t)blockIdx.z * (BATCH * 64);
#pragma unroll
  for (int tw = 0; tw < 2; ++tw) {
    int n0 = wn * 32 + tw * 16 + quad * 4;
#pragma unroll
    for (int tb = 0; tb < 4; ++tb) {
      int b = am0 + wm * 64 + tb * 16 + m16;
      *(f32x4*)(lp + (size_t)b * 64 + n0) = acc[tw][tb];
    }
  }
}

// ------------- sigmoid + tree product -> g_mix, and out := mix @ b2s -------------
__global__ __launch_bounds__(256) void sigmoid_seed_kernel(
    const float* __restrict__ nb, const float* __restrict__ b2,
    float* __restrict__ out) {
  __shared__ float sig[4][64];
  __shared__ float smix[4][64];
  const int t = threadIdx.x;
  const int b0 = blockIdx.x * 4;
  const int row = t >> 6, n = t & 63;
  {
    float s = 0.f;
#pragma unroll
    for (int z = 0; z < LZ; ++z)
      s += g_lpart[(size_t)z * (BATCH * 64) + (size_t)b0 * 64 + t];
    float bias = (n < 63) ? nb[n] : 0.f;
    sig[row][n] = 1.f / (1.f + __expf(-(s + bias)));
  }
  __syncthreads();
  {
    float p = 1.f;
#pragma unroll
    for (int d = 0; d < FDEPTH; ++d) {
      int node = (1 << d) - 1 + (n >> (FDEPTH - d));
      int bit = (n >> (FDEPTH - 1 - d)) & 1;
      float s = sig[row][node];
      p *= bit ? s : (1.f - s);
    }
    smix[row][n] = p;
    g_mix[(size_t)(b0 + row) * 64 + n] = p;
  }
  __syncthreads();
#pragma unroll
  for (int c = 0; c < 2; ++c) {
    int o = t + c * 256;
    float acc0 = 0.f, acc1 = 0.f, acc2 = 0.f, acc3 = 0.f;
    for (int l = 0; l < 64; ++l) {
      float bv = b2[(size_t)l * 512 + o];
      acc0 += smix[0][l] * bv;
      acc1 += smix[1][l] * bv;
      acc2 += smix[2][l] * bv;
      acc3 += smix[3][l] * bv;
    }
    out[(size_t)(b0 + 0) * 512 + o] = acc0;
    out[(size_t)(b0 + 1) * 512 + o] = acc1;
    out[(size_t)(b0 + 2) * 512 + o] = acc2;
    out[(size_t)(b0 + 3) * 512 + o] = acc3;
  }
}

// ------------- MFMA GEMM, weight-first (C: 4 consecutive out-cols / thread) -------------
// MODE 1: H'(b,n) = mix * relu(Xb @ W1t^T + b1) -> u16x4 direct stores.
// MODE 2: part[z](b,o) = Hb @ W2t^T  (split-K partials, f32x4 stores).
template <int MODE>
__global__ __launch_bounds__(256) void gemm_kernel(const float* __restrict__ b1) {
  constexpr int BM = 128, BN = 128, BK = 64;
  constexpr int K = (MODE == 1) ? 1024 : 4096;
  constexpr int LD = K;
  constexpr int KSPLIT = (MODE == 1) ? 1 : ZSPL;

  __shared__ u16 lsA[BM * BK];  // batch rows (second operand)
  __shared__ u16 lsB[BN * BK];  // weight rows (first operand)

  const u16* __restrict__ A = (MODE == 1) ? g_Xb : g_Hb;
  const u16* __restrict__ Bm = (MODE == 1) ? g_W1t : g_W2t;

  const int t = threadIdx.x;
  const int wv = t >> 6, ln = t & 63;
  const int wm = wv >> 1, wn = wv & 1;  // wm: batch half, wn: col half
  const int quad = ln >> 4, m16 = ln & 15;
  const int am0 = blockIdx.y * BM;
  const int bn0 = blockIdx.x * BN;
  const int kbeg = blockIdx.z * (K / KSPLIT);
  const int kend = kbeg + K / KSPLIT;

  f32x4 acc[4][4] = {};  // [tw: col tile][tb: batch tile]

  for (int kc = kbeg; kc < kend; kc += BK) {
#pragma unroll
    for (int i = 0; i < 4; ++i) {
      int id = i * 256 + t;
      int row = id >> 3;
      int c8 = (id & 7) ^ (row & 7);
      async16(A + (size_t)(am0 + row) * LD + kc + c8 * 8, lsA + (i * 256 + wv * 64) * 8);
    }
#pragma unroll
    for (int i = 0; i < 4; ++i) {
      int id = i * 256 + t;
      int row = id >> 3;
      int c8 = (id & 7) ^ (row & 7);
      async16(Bm + (size_t)(bn0 + row) * LD + kc + c8 * 8, lsB + (i * 256 + wv * 64) * 8);
    }
    __syncthreads();
#pragma unroll
    for (int ks = 0; ks < 2; ++ks) {
      bf16x8 wF[4], xF[4];
#pragma unroll
      for (int tw = 0; tw < 4; ++tw) {
        int row = wn * 64 + tw * 16 + m16;
        wF[tw] = *(const bf16x8*)(lsB + row * BK + ((ks * 4 + quad) ^ (row & 7)) * 8);
      }
#pragma unroll
      for (int tb = 0; tb < 4; ++tb) {
        int row = wm * 64 + tb * 16 + m16;
        xF[tb] = *(const bf16x8*)(lsA + row * BK + ((ks * 4 + quad) ^ (row & 7)) * 8);
      }
#pragma unroll
      for (int tw = 0; tw < 4; ++tw)
#pragma unroll
        for (int tb = 0; tb < 4; ++tb)
          acc[tw][tb] = __builtin_amdgcn_mfma_f32_16x16x32_bf16(wF[tw], xF[tb], acc[tw][tb], 0, 0, 0);
    }
    __syncthreads();
  }

  if (MODE == 1) {
    const int leaf = (bn0 >> 6) + wn;
#pragma unroll
    for (int tw = 0; tw < 4; ++tw) {
      int n0g = bn0 + wn * 64 + tw * 16 + quad * 4;
      float4 b1v = *(const float4*)(b1 + n0g);
#pragma unroll
      for (int tb = 0; tb < 4; ++tb) {
        int bg = am0 + wm * 64 + tb * 16 + m16;
        float mixv = g_mix[(size_t)bg * 64 + leaf];
        f32x4 a = acc[tw][tb];
        u16x4 pk;
        pk[0] = f2b(fmaxf(a[0] + b1v.x, 0.f) * mixv);
        pk[1] = f2b(fmaxf(a[1] + b1v.y, 0.f) * mixv);
        pk[2] = f2b(fmaxf(a[2] + b1v.z, 0.f) * mixv);
        pk[3] = f2b(fmaxf(a[3] + b1v.w, 0.f) * mixv);
        *(u16x4*)(g_Hb + (size_t)bg * NH + n0g) = pk;
      }
    }
  } else {
    float* part = g_part + (size_t)blockIdx.z * ((size_t)BATCH * OUTF);
#pragma unroll
    for (int tw = 0; tw < 4; ++tw) {
      int og = bn0 + wn * 64 + tw * 16 + quad * 4;
#pragma unroll
      for (int tb = 0; tb < 4; ++tb) {
        int bg = am0 + wm * 64 + tb * 16 + m16;
        *(f32x4*)(part + (size_t)bg * OUTF + og) = acc[tw][tb];
      }
    }
  }
}

// ------------- out += sum_z part[z] -------------
__global__ __launch_bounds__(256) void reduce_kernel(float* __restrict__ out) {
  int i = (blockIdx.x * 256 + threadIdx.x) * 4;
  float4 s = *(const float4*)(out + i);  // seed = mix @ b2s
#pragma unroll
  for (int z = 0; z < ZSPL; ++z) {
    const float4 p = *(const float4*)(g_part + (size_t)z * BATCH * OUTF + i);
    s.x += p.x; s.y += p.y; s.z += p.z; s.w += p.w;
  }
  *(float4*)(out + i) = s;
}

extern "C" void kernel_launch(void* const* d_in, const int* in_sizes, int n_in,
                              void* d_out, int out_size, void* d_ws, size_t ws_size,
                              hipStream_t stream) {
  const float* x = (const float*)d_in[0];
  const float* nw = (const float*)d_in[1];
  const float* nb = (const float*)d_in[2];
  const float* w1s = (const float*)d_in[3];
  const float* b1s = (const float*)d_in[4];
  const float* w2s = (const float*)d_in[5];
  const float* b2s = (const float*)d_in[6];
  float* out = (float*)d_out;
  (void)d_ws; (void)ws_size;

  hipLaunchKernelGGL(cast_x_kernel, dim3(2048), dim3(256), 0, stream, x);
  hipLaunchKernelGGL(cast_nw_kernel, dim3(64), dim3(256), 0, stream, nw);
  hipLaunchKernelGGL(transpose_cast_kernel, dim3(1, 16, 64), dim3(256), 0, stream,
                     w1s, 0, 1024, 64);
  hipLaunchKernelGGL(transpose_cast_kernel, dim3(8, 64, 1), dim3(256), 0, stream,
                     w2s, 1, 4096, 512);
  hipLaunchKernelGGL(logits_kernel, dim3(1, 32, LZ), dim3(256), 0, stream);
  hipLaunchKernelGGL(sigmoid_seed_kernel, dim3(1024), dim3(256), 0, stream,
                     nb, b2s, out);
  hipLaunchKernelGGL(gemm_kernel<1>, dim3(32, 32, 1), dim3(256), 0, stream, b1s);
  hipLaunchKernelGGL(gemm_kernel<2>, dim3(4, 32, ZSPL), dim3(256), 0, stream, b1s);
  hipLaunchKernelGGL(reduce_kernel, dim3(2048), dim3(256), 0, stream, out);
}